// Round 7
// baseline (1630.602 us; speedup 1.0000x reference)
//
#include <hip/hip_runtime.h>
#include <cstdint>
#include <cstddef>

#define H_ 64
#define W_ 64
#define T_ 32
#define CIN_ 16
#define COUT_ 64
#define K_ 432
#define TH_ 4
#define TW_ 16
#define WR_ 6          // window rows: 4 + 2 halo
#define WC_ 24         // padded window cols (18 used)
#define WSZ_ (WR_ * WC_)     // 144
#define XTOT_ (CIN_ * WSZ_)  // 2304
#define NTHR_ 1024

// ---- prep: w_t[k][cout] f32, Gram d64[64][64] f64, inv64[64] f64 ----
__global__ void prep(const float* __restrict__ w, float* __restrict__ w_t,
                     double* __restrict__ d64, double* __restrict__ inv64) {
    const int i = blockIdx.x;   // cout row
    const int j = threadIdx.x;  // 0..63
    const float* wi = w + i * K_;
    const float* wj = w + j * K_;
    double acc = 0.0;
    for (int k = 0; k < K_; ++k) acc += (double)wi[k] * (double)wj[k];
    d64[i * 64 + j] = acc;
    if (i == j) inv64[i] = 1.0 / (acc + 1e-8);
    for (int k = j; k < K_; k += 64) w_t[k * 64 + i] = wi[k];
}

// opaque VGPR value: defeats uniformity analysis -> forces VMEM (vmcnt) loads,
// and (inside the t-loop) defeats LICM hoisting of the weight loads.
__device__ __forceinline__ intptr_t opaque_i(intptr_t v) {
    asm volatile("" : "+v"(v));
    return v;
}

// ---- fused conv3d + spiking recurrence ----
// Read-once-per-slice: at step t read slice z=t+1 only (144 ds_read/wave/t),
// applying its 3 dz-roles to rotating f64 accumulators a0/a1/a2.
// Weights streamed via per-lane VMEM float4 loads (same addr across lanes).
__launch_bounds__(NTHR_, 1)
__global__ void fused_snn(const float* __restrict__ xg,
                          const float* __restrict__ beta_g, const float* __restrict__ bias_g,
                          const float* __restrict__ w_t, const double* __restrict__ d64,
                          const double* __restrict__ inv64, float* __restrict__ out) {
    __shared__ __align__(16) float x_win[2 * XTOT_];        // 18432 B, slot = z&1
    __shared__ __align__(16) double d_lds[64 * 65];         // 33280 B (padded rows)
    __shared__ unsigned int masks[2][64][2];                // 1024 B

    const int tid = threadIdx.x;
    const int b   = blockIdx.x;          // batch 0..3
    const int ty0 = blockIdx.y * TH_;
    const int tx0 = blockIdx.z * TW_;

    const int wv   = __builtin_amdgcn_readfirstlane(tid >> 6);  // wave 0..15
    const int lane = tid & 63;
    const int py   = lane >> 4;          // 0..3
    const int px   = lane & 15;          // 0..15
    const int c0   = wv * 4;             // wave owns couts [c0, c0+4)
    const int xoff = py * WC_ + px;

    for (int i = tid; i < 4096; i += NTHR_)
        d_lds[(i >> 6) * 65 + (i & 63)] = d64[i];
    if (tid < 128) masks[1][tid >> 1][tid & 1] = 0u;  // rbuf for t=0

    // stage slices z=0,1 into slots 0,1
    for (int z = 0; z < 2; ++z) {
        for (int i = tid; i < XTOT_; i += NTHR_) {
            int cin = i / WSZ_;
            int r2  = i - cin * WSZ_;
            int yy  = r2 / WC_;
            int xx  = r2 - yy * WC_;
            if (xx >= TW_ + 2) continue;        // pad cols never read
            int gy = ty0 - 1 + yy, gx = tx0 - 1 + xx;
            float v = 0.f;
            if (gy >= 0 && gy < H_ && gx >= 0 && gx < W_)
                v = xg[((size_t)(b * CIN_ + cin) * T_ + z) * (H_ * W_) + gy * W_ + gx];
            x_win[z * XTOT_ + i] = v;
        }
    }

    const double beta = (double)beta_g[0];
    const double omb  = 1.0 - beta;
    double inv_[4], bb[4];
#pragma unroll
    for (int ci = 0; ci < 4; ++ci) {
        inv_[ci] = inv64[c0 + ci];
        bb[ci]   = (double)bias_g[c0 + ci];
    }
    double mem[4] = {0.0, 0.0, 0.0, 0.0};
    double a0[4] = {}, a1[4] = {}, a2[4] = {};   // conv acc for out[t], out[t+1], out[t+2]

    // base byte-ptr to (k=0, c0), held in VGPRs (opaque) -> VMEM loads
    const char* wbase = (const char*)opaque_i((intptr_t)w_t + (intptr_t)(c0 * 4));

    // prefetch/staging index precompute (3 elems max per thread)
    int  pf_loff[3];
    size_t pf_goff[3];
    bool pf_use[3], pf_in[3];
#pragma unroll
    for (int r = 0; r < 3; ++r) {
        int i = tid + r * NTHR_;
        int cin = i / WSZ_;
        int r2  = i - cin * WSZ_;
        int yy  = r2 / WC_;
        int xx  = r2 - yy * WC_;
        pf_loff[r] = i;
        int gy = ty0 - 1 + yy, gx = tx0 - 1 + xx;
        bool ok = (i < XTOT_) && (xx < TW_ + 2);
        pf_use[r] = ok;
        pf_in[r]  = ok && gy >= 0 && gy < H_ && gx >= 0 && gx < W_;
        pf_goff[r] = (size_t)(b * CIN_ + cin) * (T_ * H_ * W_) + (size_t)gy * W_ + gx;
    }

    __syncthreads();   // staging of z=0,1 + d_lds visible

    // ---- prologue: slice z=0 contributes dz=1 -> a0 (out[0]), dz=0 -> a1 (out[1]) ----
    for (int g = 0; g < 8; ++g) {
        float xv[2][9];
#pragma unroll
        for (int c2 = 0; c2 < 2; ++c2) {
            const int base = (g * 2 + c2) * WSZ_ + xoff;
#pragma unroll
            for (int dy = 0; dy < 3; ++dy)
#pragma unroll
                for (int dx = 0; dx < 3; ++dx)
                    xv[c2][dy * 3 + dx] = x_win[base + dy * WC_ + dx];
        }
#pragma unroll
        for (int r = 0; r < 2; ++r) {
            const int dz = 1 - r;
            float c[4] = {0.f, 0.f, 0.f, 0.f};
#pragma unroll
            for (int c2 = 0; c2 < 2; ++c2) {
                const char* wp = wbase + (intptr_t)(((g * 2 + c2) * 27 + dz * 9) * 256);
#pragma unroll
                for (int p = 0; p < 9; ++p) {
                    const float4 wq = *(const float4*)(wp + p * 256);
                    const float xq = xv[c2][p];
                    c[0] = fmaf(wq.x, xq, c[0]);
                    c[1] = fmaf(wq.y, xq, c[1]);
                    c[2] = fmaf(wq.z, xq, c[2]);
                    c[3] = fmaf(wq.w, xq, c[3]);
                }
            }
#pragma unroll
            for (int ci = 0; ci < 4; ++ci) {
                if (r == 0) a0[ci] += (double)c[ci];
                else        a1[ci] += (double)c[ci];
            }
        }
    }

    for (int t = 0; t < T_; ++t) {
        __syncthreads();   // A: prev staging writes + prev mask ORs visible
        if (tid < 128) masks[t & 1][tid >> 1][tid & 1] = 0u;  // clear wbuf

        // prefetch slice z=t+2 into regs (hidden under conv)
        float R[3];
        const int zp = t + 2;
        if (zp < T_) {
#pragma unroll
            for (int r = 0; r < 3; ++r) {
                R[r] = 0.f;
                if (pf_in[r]) R[r] = xg[pf_goff[r] + (size_t)zp * (H_ * W_)];
            }
        }

        // re-opaque each iter: keeps weight loads inside the loop (no LICM blowup)
        const char* wvm = (const char*)opaque_i((intptr_t)wbase);

        // ---- conv: read ONLY slice z=t+1 (144 ds_read); apply 3 dz-roles ----
        const int zc = t + 1;
        if (zc < T_) {
            const int sb = (zc & 1) * XTOT_ + xoff;
            for (int g = 0; g < 8; ++g) {
                float xv[2][9];
#pragma unroll
                for (int c2 = 0; c2 < 2; ++c2) {
                    const int base = sb + (g * 2 + c2) * WSZ_;
#pragma unroll
                    for (int dy = 0; dy < 3; ++dy)
#pragma unroll
                        for (int dx = 0; dx < 3; ++dx)
                            xv[c2][dy * 3 + dx] = x_win[base + dy * WC_ + dx];
                }
                // r=0: dz=2 -> a0 (out[t]); r=1: dz=1 -> a1; r=2: dz=0 -> a2
#pragma unroll
                for (int r = 0; r < 3; ++r) {
                    const int dz = 2 - r;
                    float c[4] = {0.f, 0.f, 0.f, 0.f};
#pragma unroll
                    for (int c2 = 0; c2 < 2; ++c2) {
                        const char* wp = wvm + (intptr_t)(((g * 2 + c2) * 27 + dz * 9) * 256);
#pragma unroll
                        for (int p = 0; p < 9; ++p) {
                            const float4 wq = *(const float4*)(wp + p * 256);
                            const float xq = xv[c2][p];
                            c[0] = fmaf(wq.x, xq, c[0]);
                            c[1] = fmaf(wq.y, xq, c[1]);
                            c[2] = fmaf(wq.z, xq, c[2]);
                            c[3] = fmaf(wq.w, xq, c[3]);
                        }
                    }
#pragma unroll
                    for (int ci = 0; ci < 4; ++ci) {
                        if      (r == 0) a0[ci] += (double)c[ci];
                        else if (r == 1) a1[ci] += (double)c[ci];
                        else             a2[ci] += (double)c[ci];
                    }
                }
            }
        }

        // ---- rst from previous spikes (sparse via bitmask), fp64 d ----
        double rstv[4] = {0.0, 0.0, 0.0, 0.0};
        const int rb = (t + 1) & 1;
#pragma unroll
        for (int wrd = 0; wrd < 2; ++wrd) {
            unsigned int m = masks[rb][lane][wrd];
            while (m) {
                int bit = __ffs(m) - 1;
                m &= m - 1;
                const double* drow = &d_lds[(wrd * 32 + bit) * 65 + c0];
#pragma unroll
                for (int ci = 0; ci < 4; ++ci) rstv[ci] += drow[ci];
            }
        }

        // ---- membrane update (a0 = completed conv_out[t]), spike, store ----
        unsigned int nib = 0u;
        const size_t obase = ((size_t)(b * COUT_ + c0) * T_ + t) * (size_t)(H_ * W_)
                           + (size_t)(ty0 + py) * W_ + (tx0 + px);
#pragma unroll
        for (int ci = 0; ci < 4; ++ci) {
            mem[ci] = (mem[ci] - rstv[ci]) * beta + a0[ci] * omb;
            const double mthr = mem[ci] * inv_[ci] - bb[ci];
            const int s = mthr > 0.0 ? 1 : 0;
            out[obase + (size_t)ci * (T_ * H_ * W_)] = (float)s;
            nib |= (unsigned int)s << ci;
        }

        __syncthreads();   // B: clears + conv reads done before ORs / staging writes
        if (nib) atomicOr(&masks[t & 1][lane][wv >> 3], nib << ((wv & 7) * 4));

        // write prefetched slice z=t+2 into slot (t+2)&1 (not read this iter)
        if (zp < T_) {
            const int so = (zp & 1) * XTOT_;
#pragma unroll
            for (int r = 0; r < 3; ++r)
                if (pf_use[r]) x_win[so + pf_loff[r]] = R[r];
        }

        // rotate accumulators (static indexing, registers only)
#pragma unroll
        for (int ci = 0; ci < 4; ++ci) {
            a0[ci] = a1[ci];
            a1[ci] = a2[ci];
            a2[ci] = 0.0;
        }
    }
}

extern "C" void kernel_launch(void* const* d_in, const int* in_sizes, int n_in,
                              void* d_out, int out_size, void* d_ws, size_t ws_size,
                              hipStream_t stream) {
    const float* x    = (const float*)d_in[0];
    const float* w    = (const float*)d_in[1];
    const float* beta = (const float*)d_in[2];
    const float* bias = (const float*)d_in[3];
    float* out = (float*)d_out;

    float*  w_t   = (float*)d_ws;                                   // 110592 B
    double* d64   = (double*)((char*)d_ws + 110592);                // 32768 B
    double* inv64 = (double*)((char*)d_ws + 110592 + 32768);        // 512 B

    prep<<<dim3(64), dim3(64), 0, stream>>>(w, w_t, d64, inv64);
    fused_snn<<<dim3(4, 16, 4), dim3(NTHR_), 0, stream>>>(x, beta, bias, w_t, d64, inv64, out);
}

// Round 8
// 515.740 us; speedup vs baseline: 3.1617x; 3.1617x over previous
//
#include <hip/hip_runtime.h>
#include <cstdint>
#include <cstddef>

#define H_ 64
#define W_ 64
#define T_ 32
#define CIN_ 16
#define COUT_ 64
#define K_ 432
#define TH_ 4
#define TW_ 16
#define WR_ 6          // window rows: 4 + 2 halo
#define WC_ 24         // padded window cols (18 used)
#define WSZ_ (WR_ * WC_)     // 144
#define XTOT_ (CIN_ * WSZ_)  // 2304
#define NSLOT_ 4
#define NTHR_ 1024

// ---- prep: w_g[cout_grp][k][4] f32 (wave-contiguous), Gram d64, inv64 ----
__global__ void prep(const float* __restrict__ w, float* __restrict__ w_g,
                     double* __restrict__ d64, double* __restrict__ inv64) {
    const int i = blockIdx.x;   // cout row
    const int j = threadIdx.x;  // 0..63
    const float* wi = w + i * K_;
    const float* wj = w + j * K_;
    double acc = 0.0;
    for (int k = 0; k < K_; ++k) acc += (double)wi[k] * (double)wj[k];
    d64[i * 64 + j] = acc;
    if (i == j) inv64[i] = 1.0 / (acc + 1e-8);
    // grouped layout: w_g[(g*K_ + k)*4 + (cout&3)], g = cout>>2
    for (int k = j; k < K_; k += 64)
        w_g[(((i >> 2) * K_) + k) * 4 + (i & 3)] = wi[k];
}

// ---- fused conv3d + spiking recurrence (R6 structure, grouped weights,
//      per-cin batched x loads) ----
__launch_bounds__(NTHR_, 1)
__global__ void fused_snn(const float* __restrict__ xg,
                          const float* __restrict__ beta_g, const float* __restrict__ bias_g,
                          const float* __restrict__ w_g, const double* __restrict__ d64,
                          const double* __restrict__ inv64, float* __restrict__ out) {
    __shared__ __align__(16) float x_win[NSLOT_ * XTOT_];   // 36864 B
    __shared__ __align__(16) double d_lds[64 * 65];         // 33280 B (padded rows)
    __shared__ unsigned int masks[2][64][2];                // 1024 B

    const int tid = threadIdx.x;
    const int b   = blockIdx.x;          // batch 0..3
    const int ty0 = blockIdx.y * TH_;
    const int tx0 = blockIdx.z * TW_;

    const int wv   = __builtin_amdgcn_readfirstlane(tid >> 6);  // wave 0..15
    const int lane = tid & 63;
    const int py   = lane >> 4;          // 0..3
    const int px   = lane & 15;          // 0..15
    const int c0   = wv * 4;             // wave owns couts [c0, c0+4)
    const int xoff = py * WC_ + px;

    // wave's contiguous weight stream (6912 B), wave-uniform -> s_load
    const float* wbase = w_g + (size_t)wv * (K_ * 4);

    for (int i = tid; i < 4096; i += NTHR_)
        d_lds[(i >> 6) * 65 + (i & 63)] = d64[i];
    if (tid < 128) masks[1][tid >> 1][tid & 1] = 0u;  // rbuf for t=0

    // stage slices z=0,1 into slots 0,1
    for (int z = 0; z < 2; ++z) {
        for (int i = tid; i < XTOT_; i += NTHR_) {
            int cin = i / WSZ_;
            int r2  = i - cin * WSZ_;
            int yy  = r2 / WC_;
            int xx  = r2 - yy * WC_;
            if (xx >= TW_ + 2) continue;        // pad cols never read
            int gy = ty0 - 1 + yy, gx = tx0 - 1 + xx;
            float v = 0.f;
            if (gy >= 0 && gy < H_ && gx >= 0 && gx < W_)
                v = xg[((size_t)(b * CIN_ + cin) * T_ + z) * (H_ * W_) + gy * W_ + gx];
            x_win[z * XTOT_ + i] = v;
        }
    }

    const double beta = (double)beta_g[0];
    const double omb  = 1.0 - beta;
    double inv_[4], bb[4];
#pragma unroll
    for (int ci = 0; ci < 4; ++ci) {
        inv_[ci] = inv64[c0 + ci];
        bb[ci]   = (double)bias_g[c0 + ci];
    }
    double mem[4];
#pragma unroll
    for (int ci = 0; ci < 4; ++ci) mem[ci] = 0.0;

    // prefetch/staging index precompute (3 elems max per thread)
    int  pf_loff[3];
    size_t pf_goff[3];
    bool pf_use[3], pf_in[3];
#pragma unroll
    for (int r = 0; r < 3; ++r) {
        int i = tid + r * NTHR_;
        int cin = i / WSZ_;
        int r2  = i - cin * WSZ_;
        int yy  = r2 / WC_;
        int xx  = r2 - yy * WC_;
        pf_loff[r] = i;
        int gy = ty0 - 1 + yy, gx = tx0 - 1 + xx;
        bool ok = (i < XTOT_) && (xx < TW_ + 2);
        pf_use[r] = ok;
        pf_in[r]  = ok && gy >= 0 && gy < H_ && gx >= 0 && gx < W_;
        pf_goff[r] = (size_t)(b * CIN_ + cin) * (T_ * H_ * W_) + (size_t)gy * W_ + gx;
    }

    for (int t = 0; t < T_; ++t) {
        __syncthreads();   // A: prev LDS writes + prev mask ORs visible
        if (tid < 128) masks[t & 1][tid >> 1][tid & 1] = 0u;  // clear wbuf

        // prefetch slice z=t+2 into regs (hidden under conv)
        float R[3];
        const int zp = t + 2;
        if (zp < T_) {
#pragma unroll
            for (int r = 0; r < 3; ++r) {
                R[r] = 0.f;
                if (pf_in[r]) R[r] = xg[pf_goff[r] + (size_t)zp * (H_ * W_)];
            }
        }

        // ---- conv: fp32 products, per-cin fp64 accumulate ----
        double accd[4];
#pragma unroll
        for (int ci = 0; ci < 4; ++ci) accd[ci] = 0.0;

        int slot_[3]; bool zok[3];
#pragma unroll
        for (int dz = 0; dz < 3; ++dz) {
            int z = t - 1 + dz;
            zok[dz]  = (z >= 0 && z < T_);
            slot_[dz] = zok[dz] ? (z & 3) : 0;
        }

        for (int cin = 0; cin < CIN_; ++cin) {
            // batch ALL x reads for this cin first (one DS-latency exposure)
            float xv[3][9];
#pragma unroll
            for (int dz = 0; dz < 3; ++dz) {
                if (!zok[dz]) continue;
                const float* xs = &x_win[slot_[dz] * XTOT_ + cin * WSZ_] + xoff;
#pragma unroll
                for (int dy = 0; dy < 3; ++dy) {
                    xv[dz][dy * 3 + 0] = xs[dy * WC_ + 0];
                    xv[dz][dy * 3 + 1] = xs[dy * WC_ + 1];
                    xv[dz][dy * 3 + 2] = xs[dy * WC_ + 2];
                }
            }
            float cacc[4];
#pragma unroll
            for (int ci = 0; ci < 4; ++ci) cacc[ci] = 0.f;
#pragma unroll
            for (int dz = 0; dz < 3; ++dz) {
                if (!zok[dz]) continue;
                // contiguous 144B weight plane for this (cin,dz)
                const float* wp = wbase + (cin * 27 + dz * 9) * 4;
#pragma unroll
                for (int dy = 0; dy < 3; ++dy) {
                    const float4 w0 = *reinterpret_cast<const float4*>(wp + (dy * 3 + 0) * 4);
                    const float4 w1 = *reinterpret_cast<const float4*>(wp + (dy * 3 + 1) * 4);
                    const float4 w2 = *reinterpret_cast<const float4*>(wp + (dy * 3 + 2) * 4);
                    const float xv0 = xv[dz][dy * 3 + 0];
                    const float xv1 = xv[dz][dy * 3 + 1];
                    const float xv2 = xv[dz][dy * 3 + 2];
                    cacc[0] = fmaf(w0.x, xv0, cacc[0]);
                    cacc[1] = fmaf(w0.y, xv0, cacc[1]);
                    cacc[2] = fmaf(w0.z, xv0, cacc[2]);
                    cacc[3] = fmaf(w0.w, xv0, cacc[3]);
                    cacc[0] = fmaf(w1.x, xv1, cacc[0]);
                    cacc[1] = fmaf(w1.y, xv1, cacc[1]);
                    cacc[2] = fmaf(w1.z, xv1, cacc[2]);
                    cacc[3] = fmaf(w1.w, xv1, cacc[3]);
                    cacc[0] = fmaf(w2.x, xv2, cacc[0]);
                    cacc[1] = fmaf(w2.y, xv2, cacc[1]);
                    cacc[2] = fmaf(w2.z, xv2, cacc[2]);
                    cacc[3] = fmaf(w2.w, xv2, cacc[3]);
                }
            }
#pragma unroll
            for (int ci = 0; ci < 4; ++ci) accd[ci] += (double)cacc[ci];
        }

        // ---- rst from previous spikes (sparse via bitmask), fp64 d ----
        double rstv[4];
#pragma unroll
        for (int ci = 0; ci < 4; ++ci) rstv[ci] = 0.0;
        const int rb = (t + 1) & 1;
#pragma unroll
        for (int wrd = 0; wrd < 2; ++wrd) {
            unsigned int m = masks[rb][lane][wrd];
            while (m) {
                int bit = __ffs(m) - 1;
                m &= m - 1;
                const double* drow = &d_lds[(wrd * 32 + bit) * 65 + c0];
#pragma unroll
                for (int ci = 0; ci < 4; ++ci) rstv[ci] += drow[ci];
            }
        }

        // ---- membrane update, spike, store ----
        unsigned int nib = 0u;
        const size_t obase = ((size_t)(b * COUT_ + c0) * T_ + t) * (size_t)(H_ * W_)
                           + (size_t)(ty0 + py) * W_ + (tx0 + px);
#pragma unroll
        for (int ci = 0; ci < 4; ++ci) {
            mem[ci] = (mem[ci] - rstv[ci]) * beta + accd[ci] * omb;
            const double mthr = mem[ci] * inv_[ci] - bb[ci];
            const int s = mthr > 0.0 ? 1 : 0;
            out[obase + (size_t)ci * (T_ * H_ * W_)] = (float)s;
            nib |= (unsigned int)s << ci;
        }

        __syncthreads();   // B: all clears + conv reads done before ORs / x writes
        if (nib) atomicOr(&masks[t & 1][lane][wv >> 3], nib << ((wv & 7) * 4));

        // write prefetched slice z=t+2 into slot (t+2)&3 (not read this iter)
        if (zp < T_) {
            const int so = (zp & 3) * XTOT_;
#pragma unroll
            for (int r = 0; r < 3; ++r)
                if (pf_use[r]) x_win[so + pf_loff[r]] = R[r];
        }
    }
}

extern "C" void kernel_launch(void* const* d_in, const int* in_sizes, int n_in,
                              void* d_out, int out_size, void* d_ws, size_t ws_size,
                              hipStream_t stream) {
    const float* x    = (const float*)d_in[0];
    const float* w    = (const float*)d_in[1];
    const float* beta = (const float*)d_in[2];
    const float* bias = (const float*)d_in[3];
    float* out = (float*)d_out;

    float*  w_g   = (float*)d_ws;                                   // 110592 B
    double* d64   = (double*)((char*)d_ws + 110592);                // 32768 B
    double* inv64 = (double*)((char*)d_ws + 110592 + 32768);        // 512 B

    prep<<<dim3(64), dim3(64), 0, stream>>>(w, w_g, d64, inv64);
    fused_snn<<<dim3(4, 16, 4), dim3(NTHR_), 0, stream>>>(x, beta, bias, w_g, d64, inv64, out);
}